// Round 14
// baseline (659.072 us; speedup 1.0000x reference)
//
#include <hip/hip_runtime.h>
#include <hip/hip_bf16.h>
#include <stdint.h>

#define M_TOTAL 16384
#define N_TOTAL 4096
#define K_TOTAL 4096
#define NT32 (K_TOTAL / 32)    // 128 K-steps of 32

typedef __attribute__((ext_vector_type(8))) short bf16x8;
typedef __attribute__((ext_vector_type(4))) float f32x4;

__device__ __forceinline__ void gload_lds16(const void* g, void* l) {
    __builtin_amdgcn_global_load_lds(
        (const __attribute__((address_space(1))) uint32_t*)g,
        (__attribute__((address_space(3))) uint32_t*)l, 16, 0, 0);
}

// ---------------------------------------------------------------------------
// Kernel 0: X f32 -> bf16.
// ---------------------------------------------------------------------------
__global__ __launch_bounds__(256) void k_convX(const float* __restrict__ X,
                                               __hip_bfloat16* __restrict__ Xb) {
    size_t t = (size_t)blockIdx.x * 256 + threadIdx.x;
    const float* p = X + t * 8;
    float4 a = *(const float4*)p;
    float4 b = *(const float4*)(p + 4);
    __hip_bfloat162 o[4] = {
        __float22bfloat162_rn(make_float2(a.x, a.y)),
        __float22bfloat162_rn(make_float2(a.z, a.w)),
        __float22bfloat162_rn(make_float2(b.x, b.y)),
        __float22bfloat162_rn(make_float2(b.z, b.w))};
    *(int4*)(Xb + t * 8) = *(int4*)&o[0];
}

// ---------------------------------------------------------------------------
// Kernel 1: packed int4 -> bf16 W[N][K].
// ---------------------------------------------------------------------------
__global__ __launch_bounds__(256) void k_dequant(const int* __restrict__ pw,
                                                 const float* __restrict__ sc,
                                                 __hip_bfloat16* __restrict__ W) {
    int t = blockIdx.x * 256 + threadIdx.x;
    int row = t >> 8;
    int w0 = (t & 255) << 3;
    const int* p = pw + (size_t)row * 2048 + w0;
    int4 q0 = *(const int4*)p;
    int4 q1 = *(const int4*)(p + 4);
    float s = sc[row * 128 + (w0 >> 4)];
    float ns8 = -8.0f * s;
    int w[8] = {q0.x, q0.y, q0.z, q0.w, q1.x, q1.y, q1.z, q1.w};
    __hip_bfloat162 o[8];
#pragma unroll
    for (int i = 0; i < 8; ++i) {
        float lo = fmaf((float)(w[i] & 15), s, ns8);
        float hi = fmaf((float)(w[i] >> 4), s, ns8);
        o[i] = __float22bfloat162_rn(make_float2(lo, hi));
    }
    __hip_bfloat16* dst = W + (size_t)row * 4096 + w0 * 2;
    *(int4*)dst = *(int4*)&o[0];
    *(int4*)(dst + 8) = *(int4*)&o[4];
}

// ---------------------------------------------------------------------------
// Kernel 2 (tier A): LAG-2 READ PIPELINE. 256x256 tile, BK=32, ring-4 LDS
// (4 x 32KB), 8 waves (2Mx4N), per-wave 128x64, mfma 16x16x32 (r8 layouts).
//
// Every ds_read issues 2 phases before its consuming MFMA -> LDS serves
// reads UNDER the MFMA clusters (the overlap r6-r13 lacked):
//   body(k), 4 phases (1 barrier each, 8 MFMA each):
//   ph1: BAR; rd q3(k);        stage A(k+2)lo; MFMA Q1(k)=rf0,1 x Bcur
//   ph2: BAR; rd q4(k);        stage A(k+2)hi; MFMA Q2(k)=rf2,3
//   ph3: VMW(2); BAR; rd B(k+1)->Bnxt, q1(k+1); stage B(k+2)lo; MFMA Q3(k)=rf4,5
//   ph4: BAR; rd q2(k+1);      stage B(k+2)hi; MFMA Q4(k)=rf6,7
// Each read -> use distance = exactly 2 phases (q3:ph1->ph3, B/q1:ph3->next
// ph1, etc). vmcnt ledger (1 gload/phase): mid-body VMW(2) drains B(k+1)
// (staged body k-1 ph3/4) exactly before its ph3 read, leaves A(k+2)'s 2.
// VMW(0) for k>=NT-2. Stage-overwrite: buf[(k+2)&3]=buf[(k-2)&3], consumed
// by body(k-2) ph4 MFMA, >=4 barriers before overwrite.
// B double-set (Bc/Ba by name, unroll 2); A quadrant sets q1S..q4S (WAR gap
// 2 phases each). LDS slot scheme = r6/r10 verified 0-conflict.
// ---------------------------------------------------------------------------
__global__ __launch_bounds__(512, 2) void k_gemm14(const __hip_bfloat16* __restrict__ Xb,
                                                   const __hip_bfloat16* __restrict__ Wb,
                                                   float* __restrict__ out) {
    __shared__ __align__(16) short L[4][16384];   // 4 bufs x (A 16KB + B 16KB)

    int bid = blockIdx.x;
    int swz = (bid & 7) * 128 + (bid >> 3);       // XCD-bijective (1024%8==0)
    int bn = swz & 15, bm = swz >> 4;
    int m0 = bm * 256, n0 = bn * 256;
    int t = threadIdx.x, lane = t & 63, wv = t >> 6;
    int wm = wv >> 2, wn = wv & 3;

    // staging: thread t -> row (t>>5)*8+(t&7) (0..127), chunk (t>>3)&3
    int srow = (t >> 5) * 8 + (t & 7);
    int scol = ((t >> 3) & 3) * 8;
    const __hip_bfloat16* gA = Xb + (size_t)(m0 + srow) * K_TOTAL + scol;
    const __hip_bfloat16* gB = Wb + (size_t)(n0 + srow) * K_TOTAL + scol;

    // part: 0=A rows0-127, 1=A rows128-255, 2=B rows0-127, 3=B rows128-255
    auto stage = [&](int T, int part) {
        const __hip_bfloat16* g = (part < 2 ? gA : gB) + (size_t)((part & 1) * 128) * K_TOTAL + T * 32;
        gload_lds16(g, &L[T & 3][part * 4096 + t * 8]);
    };

    const int offL = ((lane & 15) >> 3) * 256 + ((lane >> 4) * 8 + (lane & 7)) * 8;
    // A frag rf: (wm*2+(rf>>2))*2048 + (rf&3)*512 + offL ; B cf: 8192+wn*2048+cf*512+offL
    const int abase = wm * 4096;
    const int bbase = 8192 + wn * 2048;

    f32x4 acc[8][4];
#pragma unroll
    for (int f = 0; f < 8; ++f)
#pragma unroll
        for (int j = 0; j < 4; ++j) acc[f][j] = (f32x4)(0.0f);

    bf16x8 q1S[2], q2S[2], q3S[2], q4S[2], Bc[4], Ba[4];

#define BAR __builtin_amdgcn_s_barrier()
#define PRI(x) __builtin_amdgcn_s_setprio(x)
#define SB0 __builtin_amdgcn_sched_barrier(0)
#define VMW(n) { asm volatile("s_waitcnt vmcnt(" #n ")" ::: "memory"); SB0; }
#define RA(Lp, rf) (*(const bf16x8*)&(Lp)[abase + ((rf) >> 2) * 2048 + ((rf) & 3) * 512 + offL])
#define RB(Lp, cf) (*(const bf16x8*)&(Lp)[bbase + (cf) * 512 + offL])
#define MM2(rb, QS, BV) { _Pragma("unroll") for (int u = 0; u < 2; ++u) \
    _Pragma("unroll") for (int cf = 0; cf < 4; ++cf) \
        acc[(rb) + u][cf] = __builtin_amdgcn_mfma_f32_16x16x32_bf16( \
            QS[u], BV[cf], acc[(rb) + u][cf], 0, 0, 0); }

#define BODY(K, BC, BN)                                                        \
    {                                                                          \
        const int k_ = (K);                                                    \
        const short* Lc = &L[k_ & 3][0];                                       \
        const short* Ln = &L[(k_ + 1) & 3][0];                                 \
        const bool gR = (k_ + 1 < NT32);                                       \
        const bool gS = (k_ + 2 < NT32);                                       \
        /* ph1 */                                                              \
        BAR;                                                                   \
        q3S[0] = RA(Lc, 4); q3S[1] = RA(Lc, 5);                                \
        if (gS) stage(k_ + 2, 0);                                              \
        SB0; PRI(1); MM2(0, q1S, BC) PRI(0);                                   \
        /* ph2 */                                                              \
        BAR;                                                                   \
        q4S[0] = RA(Lc, 6); q4S[1] = RA(Lc, 7);                                \
        if (gS) stage(k_ + 2, 1);                                              \
        SB0; PRI(1); MM2(2, q2S, BC) PRI(0);                                   \
        /* ph3 */                                                              \
        if (k_ < NT32 - 2) { VMW(2) } else { VMW(0) }                          \
        BAR;                                                                   \
        if (gR) {                                                              \
            BN[0] = RB(Ln, 0); BN[1] = RB(Ln, 1);                              \
            BN[2] = RB(Ln, 2); BN[3] = RB(Ln, 3);                              \
            q1S[0] = RA(Ln, 0); q1S[1] = RA(Ln, 1);                            \
        }                                                                      \
        if (gS) stage(k_ + 2, 2);                                              \
        SB0; PRI(1); MM2(4, q3S, BC) PRI(0);                                   \
        /* ph4 */                                                              \
        BAR;                                                                   \
        if (gR) { q2S[0] = RA(Ln, 2); q2S[1] = RA(Ln, 3); }                    \
        if (gS) stage(k_ + 2, 3);                                              \
        SB0; PRI(1); MM2(6, q4S, BC) PRI(0);                                   \
    }

    // ---- prologue: stage tiles 0,1; drain tile 0; pre-read tile 0 frags ----
    stage(0, 0); stage(0, 1); stage(0, 2); stage(0, 3);
    stage(1, 0); stage(1, 1); stage(1, 2); stage(1, 3);
    VMW(4);
    BAR;
    {
        const short* L0 = &L[0][0];
        Bc[0] = RB(L0, 0); Bc[1] = RB(L0, 1); Bc[2] = RB(L0, 2); Bc[3] = RB(L0, 3);
        q1S[0] = RA(L0, 0); q1S[1] = RA(L0, 1);
        q2S[0] = RA(L0, 2); q2S[1] = RA(L0, 3);
    }

    for (int k2 = 0; k2 < NT32 / 2; ++k2) {
        BODY(2 * k2, Bc, Ba);
        BODY(2 * k2 + 1, Ba, Bc);
    }
#undef BODY
#undef RA
#undef RB
#undef MM2
#undef BAR
#undef PRI
#undef SB0
#undef VMW

    // ---- epilogue: C/D layout col=lane&15, row=(lane>>4)*4+reg ----
    int col0 = n0 + wn * 64 + (lane & 15);
    int row0 = m0 + wm * 128 + (lane >> 4) * 4;
#pragma unroll
    for (int f = 0; f < 8; ++f)
#pragma unroll
        for (int j = 0; j < 4; ++j) {
            f32x4 v = acc[f][j];
            int r = row0 + f * 16;
            int c = col0 + j * 16;
#pragma unroll
            for (int q = 0; q < 4; ++q)
                out[(size_t)(r + q) * N_TOTAL + c] = v[q];
        }
}

// ---------------------------------------------------------------------------
// Tier B: m97-structure GEMM, A reg-staged from f32 X (round-5 verified).
// ---------------------------------------------------------------------------
__global__ __launch_bounds__(256) void k_gemm2b(const float* __restrict__ X,
                                                const __hip_bfloat16* __restrict__ Wb,
                                                float* __restrict__ out) {
    __shared__ __align__(16) short As[128 * 32];
    __shared__ __align__(16) short Bs[128 * 32];
    int bid = blockIdx.x;
    int swz = (bid & 7) * 512 + (bid >> 3);
    int bn = swz & 31, bm = swz >> 5;
    int m0 = bm * 128, n0 = bn * 128;
    int t = threadIdx.x, lane = t & 63, wv = t >> 6;
    int wr = wv >> 1, wc = wv & 1;
    f32x4 acc[4][4];
#pragma unroll
    for (int i = 0; i < 4; ++i)
#pragma unroll
        for (int j = 0; j < 4; ++j) acc[i][j] = (f32x4)(0.0f);
    int arow = t >> 2, acol = (t & 3) * 8;
    const float* Agf0 = X + (size_t)(m0 + arow) * K_TOTAL + acol;
    const float* Agf1 = Agf0 + (size_t)64 * K_TOTAL;
    const __hip_bfloat16* Bg0 = Wb + (size_t)(n0 + arow) * K_TOTAL + acol;
    const __hip_bfloat16* Bg1 = Bg0 + (size_t)64 * K_TOTAL;
    float4 xa0 = *(const float4*)(Agf0), xa1 = *(const float4*)(Agf0 + 4);
    float4 xb0 = *(const float4*)(Agf1), xb1 = *(const float4*)(Agf1 + 4);
    for (int kt = 0; kt < NT32; ++kt) {
        if (kt) __syncthreads();
        __hip_bfloat162 oa[4] = {
            __float22bfloat162_rn(make_float2(xa0.x, xa0.y)),
            __float22bfloat162_rn(make_float2(xa0.z, xa0.w)),
            __float22bfloat162_rn(make_float2(xa1.x, xa1.y)),
            __float22bfloat162_rn(make_float2(xa1.z, xa1.w))};
        __hip_bfloat162 ob[4] = {
            __float22bfloat162_rn(make_float2(xb0.x, xb0.y)),
            __float22bfloat162_rn(make_float2(xb0.z, xb0.w)),
            __float22bfloat162_rn(make_float2(xb1.x, xb1.y)),
            __float22bfloat162_rn(make_float2(xb1.z, xb1.w))};
        *(int4*)&As[t * 8] = *(int4*)&oa[0];
        *(int4*)&As[2048 + t * 8] = *(int4*)&ob[0];
        gload_lds16(Bg0 + kt * 32, &Bs[t * 8]);
        gload_lds16(Bg1 + kt * 32, &Bs[2048 + t * 8]);
        __syncthreads();
        if (kt < NT32 - 1) {
            int ko = (kt + 1) * 32;
            xa0 = *(const float4*)(Agf0 + ko);
            xa1 = *(const float4*)(Agf0 + ko + 4);
            xb0 = *(const float4*)(Agf1 + ko);
            xb1 = *(const float4*)(Agf1 + ko + 4);
        }
        bf16x8 a[4], b[4];
        int ro = (lane & 15) * 32 + (lane >> 4) * 8;
#pragma unroll
        for (int i = 0; i < 4; ++i)
            a[i] = *(const bf16x8*)&As[(wr * 64 + i * 16) * 32 + ro];
#pragma unroll
        for (int j = 0; j < 4; ++j)
            b[j] = *(const bf16x8*)&Bs[(wc * 64 + j * 16) * 32 + ro];
#pragma unroll
        for (int i = 0; i < 4; ++i)
#pragma unroll
            for (int j = 0; j < 4; ++j)
                acc[i][j] = __builtin_amdgcn_mfma_f32_16x16x32_bf16(a[i], b[j], acc[i][j], 0, 0, 0);
    }
    int col0 = n0 + wc * 64 + (lane & 15);
    int row0 = m0 + wr * 64 + (lane >> 4) * 4;
#pragma unroll
    for (int i = 0; i < 4; ++i)
#pragma unroll
        for (int j = 0; j < 4; ++j) {
            f32x4 v = acc[i][j];
            int r = row0 + i * 16, c = col0 + j * 16;
#pragma unroll
            for (int q = 0; q < 4; ++q)
                out[(size_t)(r + q) * N_TOTAL + c] = v[q];
        }
}

extern "C" void kernel_launch(void* const* d_in, const int* in_sizes, int n_in,
                              void* d_out, int out_size, void* d_ws, size_t ws_size,
                              hipStream_t stream) {
    const float* X = (const float*)d_in[0];
    const int* PW = (const int*)d_in[1];
    const float* SC = (const float*)d_in[2];
    float* OUT = (float*)d_out;

    const size_t needW = (size_t)N_TOTAL * K_TOTAL * 2;            // 33.5 MB
    const size_t needX = needW + (size_t)M_TOTAL * K_TOTAL * 2;    // +134 MB

    if (ws_size >= needX) {
        __hip_bfloat16* Wb = (__hip_bfloat16*)d_ws;
        __hip_bfloat16* Xb = (__hip_bfloat16*)((char*)d_ws + needW);
        k_convX<<<dim3(32768), dim3(256), 0, stream>>>(X, Xb);
        k_dequant<<<dim3(4096), dim3(256), 0, stream>>>(PW, SC, Wb);
        k_gemm14<<<dim3((M_TOTAL / 256) * (N_TOTAL / 256)), dim3(512), 0, stream>>>(Xb, Wb, OUT);
    } else if (ws_size >= needW) {
        __hip_bfloat16* Wb = (__hip_bfloat16*)d_ws;
        k_dequant<<<dim3(4096), dim3(256), 0, stream>>>(PW, SC, Wb);
        k_gemm2b<<<dim3((M_TOTAL / 128) * (N_TOTAL / 128)), dim3(256), 0, stream>>>(X, Wb, OUT);
    }
}

// Round 15
// 569.728 us; speedup vs baseline: 1.1568x; 1.1568x over previous
//
#include <hip/hip_runtime.h>
#include <hip/hip_bf16.h>
#include <stdint.h>

#define M_TOTAL 16384
#define N_TOTAL 4096
#define K_TOTAL 4096
#define NSTEP (K_TOTAL / 64)   // 64 K-steps of 64
#define NT32 (K_TOTAL / 32)

typedef __attribute__((ext_vector_type(8))) short bf16x8;
typedef __attribute__((ext_vector_type(4))) float f32x4;

__device__ __forceinline__ void gload_lds16(const void* g, void* l) {
    __builtin_amdgcn_global_load_lds(
        (const __attribute__((address_space(1))) uint32_t*)g,
        (__attribute__((address_space(3))) uint32_t*)l, 16, 0, 0);
}

// ---------------------------------------------------------------------------
// Kernel 0: X f32 -> bf16.
// ---------------------------------------------------------------------------
__global__ __launch_bounds__(256) void k_convX(const float* __restrict__ X,
                                               __hip_bfloat16* __restrict__ Xb) {
    size_t t = (size_t)blockIdx.x * 256 + threadIdx.x;
    const float* p = X + t * 8;
    float4 a = *(const float4*)p;
    float4 b = *(const float4*)(p + 4);
    __hip_bfloat162 o[4] = {
        __float22bfloat162_rn(make_float2(a.x, a.y)),
        __float22bfloat162_rn(make_float2(a.z, a.w)),
        __float22bfloat162_rn(make_float2(b.x, b.y)),
        __float22bfloat162_rn(make_float2(b.z, b.w))};
    *(int4*)(Xb + t * 8) = *(int4*)&o[0];
}

// ---------------------------------------------------------------------------
// Kernel 1: packed int4 -> bf16 W[N][K].
// ---------------------------------------------------------------------------
__global__ __launch_bounds__(256) void k_dequant(const int* __restrict__ pw,
                                                 const float* __restrict__ sc,
                                                 __hip_bfloat16* __restrict__ W) {
    int t = blockIdx.x * 256 + threadIdx.x;
    int row = t >> 8;
    int w0 = (t & 255) << 3;
    const int* p = pw + (size_t)row * 2048 + w0;
    int4 q0 = *(const int4*)p;
    int4 q1 = *(const int4*)(p + 4);
    float s = sc[row * 128 + (w0 >> 4)];
    float ns8 = -8.0f * s;
    int w[8] = {q0.x, q0.y, q0.z, q0.w, q1.x, q1.y, q1.z, q1.w};
    __hip_bfloat162 o[8];
#pragma unroll
    for (int i = 0; i < 8; ++i) {
        float lo = fmaf((float)(w[i] & 15), s, ns8);
        float hi = fmaf((float)(w[i] >> 4), s, ns8);
        o[i] = __float22bfloat162_rn(make_float2(lo, hi));
    }
    __hip_bfloat16* dst = W + (size_t)row * 4096 + w0 * 2;
    *(int4*)dst = *(int4*)&o[0];
    *(int4*)(dst + 8) = *(int4*)&o[4];
}

// ---------------------------------------------------------------------------
// Kernel 2 (tier A): r8's EXACT schedule (phases/barriers/stage rotation/
// vmcnt(4) ledger — race-audited, 578us) with ONLY the LDS layout changed
// to the m201-documented one:
//   half-tile = [128 rows][64 k] bf16 ROW-MAJOR (16KB), st_16x32 XOR:
//     short_idx' = idx ^ (((idx>>8)&1)<<4)   i.e.  k' = k ^ (((r>>2)&1)<<4)
//   DMA dest linear (thread t -> shorts [8t,8t+8)); SOURCE pre-XORed:
//     thread t, gload g: row = g*64 + (t>>3), k = (t&7)*8 ^ ((t>>5)&1)<<4
//   ds_read applies same XOR via per-lane const kx = kb ^ ((l15>>2)&1)<<4:
//     A(rf,kk):  idx = rf*1024 + kk*32 + l15*64 + kx
//     B(cf,kk):  idx = (wn&1)*4096 + cf*1024 + kk*32 + l15*64 + kx
// Controlled experiment: any perf delta vs r8 = layout effect.
// ---------------------------------------------------------------------------
__global__ __launch_bounds__(512, 2) void k_gemm15(const __hip_bfloat16* __restrict__ Xb,
                                                   const __hip_bfloat16* __restrict__ Wb,
                                                   float* __restrict__ out) {
    __shared__ __align__(16) short L[2][2][2][8192];  // [buf][A/B][half][16KB]

    int bid = blockIdx.x;
    int swz = (bid & 7) * 128 + (bid >> 3);           // XCD-bijective (1024%8==0)
    int bn = swz & 15, bm = swz >> 4;
    int m0 = bm * 256, n0 = bn * 256;
    int t = threadIdx.x, lane = t & 63, wv = t >> 6;
    int wm = wv >> 2, wn = wv & 3, wnh = wn >> 1;

    // staging source (pre-swizzled): row g*64+(t>>3), k = (t&7)*8 ^ ((t>>5)&1)<<4
    int srow = t >> 3;                       // 0..63 (g adds 64)
    int sko = ((t & 7) * 8) ^ (((t >> 5) & 1) << 4);
    const __hip_bfloat16* gA = Xb + (size_t)(m0 + srow) * K_TOTAL + sko;
    const __hip_bfloat16* gB = Wb + (size_t)(n0 + srow) * K_TOTAL + sko;

    auto stA = [&](int b, int h, int s_) {
        gload_lds16(gA + (size_t)(h * 128) * K_TOTAL + s_ * 64, &L[b][0][h][t * 8]);
        gload_lds16(gA + (size_t)(h * 128 + 64) * K_TOTAL + s_ * 64, &L[b][0][h][4096 + t * 8]);
    };
    auto stB = [&](int b, int h, int s_) {
        gload_lds16(gB + (size_t)(h * 128) * K_TOTAL + s_ * 64, &L[b][1][h][t * 8]);
        gload_lds16(gB + (size_t)(h * 128 + 64) * K_TOTAL + s_ * 64, &L[b][1][h][4096 + t * 8]);
    };

    // frag-read lane constants
    const int l15 = lane & 15;
    const int kb = (lane >> 4) * 8;                       // 0,8,16,24
    const int kx = kb ^ (((l15 >> 2) & 1) << 4);          // XOR folded per-lane
    const int roff = l15 * 64 + kx;
    const int bco = (wn & 1) * 4096;

    f32x4 acc[8][4];
#pragma unroll
    for (int f = 0; f < 8; ++f)
#pragma unroll
        for (int j = 0; j < 4; ++j) acc[f][j] = (f32x4)(0.0f);

    bf16x8 Af[8], Bq01[4], Bq23[4];

#define RD_A(rfb) { _Pragma("unroll") for (int rf = 0; rf < 4; ++rf) { \
        Af[rf * 2]     = *(const bf16x8*)&LA[((rfb) + rf) * 1024 + roff]; \
        Af[rf * 2 + 1] = *(const bf16x8*)&LA[((rfb) + rf) * 1024 + 32 + roff]; } }
#define RD_B(dst, cfb) { _Pragma("unroll") for (int cf = 0; cf < 2; ++cf) { \
        dst[cf * 2]     = *(const bf16x8*)&LB[bco + ((cfb) + cf) * 1024 + roff]; \
        dst[cf * 2 + 1] = *(const bf16x8*)&LB[bco + ((cfb) + cf) * 1024 + 32 + roff]; } }
#define MM16(rfb, Bv, cfb) { _Pragma("unroll") for (int kk = 0; kk < 2; ++kk) \
        _Pragma("unroll") for (int rf = 0; rf < 4; ++rf) \
        _Pragma("unroll") for (int cf = 0; cf < 2; ++cf) \
            acc[(rfb) + rf][(cfb) + cf] = __builtin_amdgcn_mfma_f32_16x16x32_bf16( \
                Af[rf * 2 + kk], Bv[cf * 2 + kk], acc[(rfb) + rf][(cfb) + cf], 0, 0, 0); }
#define BAR __builtin_amdgcn_s_barrier()
#define PRI(x) __builtin_amdgcn_s_setprio(x)
#define VMW(n) { asm volatile("s_waitcnt vmcnt(" #n ")" ::: "memory"); \
                 __builtin_amdgcn_sched_barrier(0); }

    // ---- prologue (r8-identical): B(0), A(0), B(1); vmcnt(4) ----
    stB(0, 0, 0); stB(0, 1, 0);
    stA(0, 0, 0); stA(0, 1, 0);
    stB(1, 0, 1); stB(1, 1, 1);
    VMW(4);
    BAR;

    for (int i = 0; i < NSTEP / 2; ++i) {
        const int s = 2 * i;
        const bool g = (s + 2 < NSTEP);
        // ======== K-step s (buf 0) ========
        {
            const short* LA = &L[0][0][wm][0];
            const short* LB = &L[0][1][wnh][0];
            // p1
            RD_A(0) RD_B(Bq01, 0)
            stA(1, 0, s + 1);
            BAR; PRI(1); MM16(0, Bq01, 0) PRI(0); BAR;
            // p2
            RD_B(Bq23, 2)
            stA(1, 1, s + 1);
            BAR; PRI(1); MM16(0, Bq23, 2) PRI(0); BAR;
            // p3
            RD_A(4)
            if (g) stB(0, 0, s + 2);
            BAR; PRI(1); MM16(4, Bq01, 0) PRI(0); BAR;
            // p4
            if (g) stB(0, 1, s + 2);
            BAR; PRI(1); MM16(4, Bq23, 2) PRI(0);
            if (g) { VMW(4) } else { VMW(0) }
            BAR;
        }
        // ======== K-step s+1 (buf 1) ========
        {
            const short* LA = &L[1][0][wm][0];
            const short* LB = &L[1][1][wnh][0];
            // p5
            RD_A(0) RD_B(Bq01, 0)
            if (g) stA(0, 0, s + 2);
            BAR; PRI(1); MM16(0, Bq01, 0) PRI(0); BAR;
            // p6
            RD_B(Bq23, 2)
            if (g) stA(0, 1, s + 2);
            BAR; PRI(1); MM16(0, Bq23, 2) PRI(0); BAR;
            // p7
            RD_A(4)
            if (g) stB(1, 0, s + 3);
            BAR; PRI(1); MM16(4, Bq01, 0) PRI(0); BAR;
            // p8
            if (g) stB(1, 1, s + 3);
            BAR; PRI(1); MM16(4, Bq23, 2) PRI(0);
            if (g) { VMW(4) } else { VMW(0) }
            BAR;
        }
    }
#undef RD_A
#undef RD_B
#undef MM16
#undef BAR
#undef PRI
#undef VMW

    // ---- epilogue: C/D layout col=lane&15, row=(lane>>4)*4+reg ----
    int col0 = n0 + wn * 64 + l15;
    int row0 = m0 + wm * 128 + (lane >> 4) * 4;
#pragma unroll
    for (int f = 0; f < 8; ++f)
#pragma unroll
        for (int j = 0; j < 4; ++j) {
            f32x4 v = acc[f][j];
            int r = row0 + f * 16;
            int c = col0 + j * 16;
#pragma unroll
            for (int q = 0; q < 4; ++q)
                out[(size_t)(r + q) * N_TOTAL + c] = v[q];
        }
}

// ---------------------------------------------------------------------------
// Tier B: m97-structure GEMM, A reg-staged from f32 X (round-5 verified).
// ---------------------------------------------------------------------------
__global__ __launch_bounds__(256) void k_gemm2b(const float* __restrict__ X,
                                                const __hip_bfloat16* __restrict__ Wb,
                                                float* __restrict__ out) {
    __shared__ __align__(16) short As[128 * 32];
    __shared__ __align__(16) short Bs[128 * 32];
    int bid = blockIdx.x;
    int swz = (bid & 7) * 512 + (bid >> 3);
    int bn = swz & 31, bm = swz >> 5;
    int m0 = bm * 128, n0 = bn * 128;
    int t = threadIdx.x, lane = t & 63, wv = t >> 6;
    int wr = wv >> 1, wc = wv & 1;
    f32x4 acc[4][4];
#pragma unroll
    for (int i = 0; i < 4; ++i)
#pragma unroll
        for (int j = 0; j < 4; ++j) acc[i][j] = (f32x4)(0.0f);
    int arow = t >> 2, acol = (t & 3) * 8;
    const float* Agf0 = X + (size_t)(m0 + arow) * K_TOTAL + acol;
    const float* Agf1 = Agf0 + (size_t)64 * K_TOTAL;
    const __hip_bfloat16* Bg0 = Wb + (size_t)(n0 + arow) * K_TOTAL + acol;
    const __hip_bfloat16* Bg1 = Bg0 + (size_t)64 * K_TOTAL;
    float4 xa0 = *(const float4*)(Agf0), xa1 = *(const float4*)(Agf0 + 4);
    float4 xb0 = *(const float4*)(Agf1), xb1 = *(const float4*)(Agf1 + 4);
    for (int kt = 0; kt < NT32; ++kt) {
        if (kt) __syncthreads();
        __hip_bfloat162 oa[4] = {
            __float22bfloat162_rn(make_float2(xa0.x, xa0.y)),
            __float22bfloat162_rn(make_float2(xa0.z, xa0.w)),
            __float22bfloat162_rn(make_float2(xa1.x, xa1.y)),
            __float22bfloat162_rn(make_float2(xa1.z, xa1.w))};
        __hip_bfloat162 ob[4] = {
            __float22bfloat162_rn(make_float2(xb0.x, xb0.y)),
            __float22bfloat162_rn(make_float2(xb0.z, xb0.w)),
            __float22bfloat162_rn(make_float2(xb1.x, xb1.y)),
            __float22bfloat162_rn(make_float2(xb1.z, xb1.w))};
        *(int4*)&As[t * 8] = *(int4*)&oa[0];
        *(int4*)&As[2048 + t * 8] = *(int4*)&ob[0];
        gload_lds16(Bg0 + kt * 32, &Bs[t * 8]);
        gload_lds16(Bg1 + kt * 32, &Bs[2048 + t * 8]);
        __syncthreads();
        if (kt < NT32 - 1) {
            int ko = (kt + 1) * 32;
            xa0 = *(const float4*)(Agf0 + ko);
            xa1 = *(const float4*)(Agf0 + ko + 4);
            xb0 = *(const float4*)(Agf1 + ko);
            xb1 = *(const float4*)(Agf1 + ko + 4);
        }
        bf16x8 a[4], b[4];
        int ro = (lane & 15) * 32 + (lane >> 4) * 8;
#pragma unroll
        for (int i = 0; i < 4; ++i)
            a[i] = *(const bf16x8*)&As[(wr * 64 + i * 16) * 32 + ro];
#pragma unroll
        for (int j = 0; j < 4; ++j)
            b[j] = *(const bf16x8*)&Bs[(wc * 64 + j * 16) * 32 + ro];
#pragma unroll
        for (int i = 0; i < 4; ++i)
#pragma unroll
            for (int j = 0; j < 4; ++j)
                acc[i][j] = __builtin_amdgcn_mfma_f32_16x16x32_bf16(a[i], b[j], acc[i][j], 0, 0, 0);
    }
    int col0 = n0 + wc * 64 + (lane & 15);
    int row0 = m0 + wr * 64 + (lane >> 4) * 4;
#pragma unroll
    for (int i = 0; i < 4; ++i)
#pragma unroll
        for (int j = 0; j < 4; ++j) {
            f32x4 v = acc[i][j];
            int r = row0 + i * 16, c = col0 + j * 16;
#pragma unroll
            for (int q = 0; q < 4; ++q)
                out[(size_t)(r + q) * N_TOTAL + c] = v[q];
        }
}

extern "C" void kernel_launch(void* const* d_in, const int* in_sizes, int n_in,
                              void* d_out, int out_size, void* d_ws, size_t ws_size,
                              hipStream_t stream) {
    const float* X = (const float*)d_in[0];
    const int* PW = (const int*)d_in[1];
    const float* SC = (const float*)d_in[2];
    float* OUT = (float*)d_out;

    const size_t needW = (size_t)N_TOTAL * K_TOTAL * 2;            // 33.5 MB
    const size_t needX = needW + (size_t)M_TOTAL * K_TOTAL * 2;    // +134 MB

    if (ws_size >= needX) {
        __hip_bfloat16* Wb = (__hip_bfloat16*)d_ws;
        __hip_bfloat16* Xb = (__hip_bfloat16*)((char*)d_ws + needW);
        k_convX<<<dim3(32768), dim3(256), 0, stream>>>(X, Xb);
        k_dequant<<<dim3(4096), dim3(256), 0, stream>>>(PW, SC, Wb);
        k_gemm15<<<dim3((M_TOTAL / 256) * (N_TOTAL / 256)), dim3(512), 0, stream>>>(Xb, Wb, OUT);
    } else if (ws_size >= needW) {
        __hip_bfloat16* Wb = (__hip_bfloat16*)d_ws;
        k_dequant<<<dim3(4096), dim3(256), 0, stream>>>(PW, SC, Wb);
        k_gemm2b<<<dim3((M_TOTAL / 128) * (N_TOTAL / 128)), dim3(256), 0, stream>>>(X, Wb, OUT);
    }
}

// Round 16
// 534.606 us; speedup vs baseline: 1.2328x; 1.0657x over previous
//
#include <hip/hip_runtime.h>
#include <hip/hip_bf16.h>
#include <stdint.h>

#define M_TOTAL 16384
#define N_TOTAL 4096
#define K_TOTAL 4096
#define NSTEP (K_TOTAL / 64)   // 64 K-steps of 64
#define NT32 (K_TOTAL / 32)

typedef __attribute__((ext_vector_type(8))) short bf16x8;
typedef __attribute__((ext_vector_type(4))) float f32x4;

__device__ __forceinline__ void gload_lds16(const void* g, void* l) {
    __builtin_amdgcn_global_load_lds(
        (const __attribute__((address_space(1))) uint32_t*)g,
        (__attribute__((address_space(3))) uint32_t*)l, 16, 0, 0);
}

// ---------------------------------------------------------------------------
// Kernel 0: X f32 -> bf16.
// ---------------------------------------------------------------------------
__global__ __launch_bounds__(256) void k_convX(const float* __restrict__ X,
                                               __hip_bfloat16* __restrict__ Xb) {
    size_t t = (size_t)blockIdx.x * 256 + threadIdx.x;
    const float* p = X + t * 8;
    float4 a = *(const float4*)p;
    float4 b = *(const float4*)(p + 4);
    __hip_bfloat162 o[4] = {
        __float22bfloat162_rn(make_float2(a.x, a.y)),
        __float22bfloat162_rn(make_float2(a.z, a.w)),
        __float22bfloat162_rn(make_float2(b.x, b.y)),
        __float22bfloat162_rn(make_float2(b.z, b.w))};
    *(int4*)(Xb + t * 8) = *(int4*)&o[0];
}

// ---------------------------------------------------------------------------
// Kernel 1: packed int4 -> bf16 W[N][K].
// ---------------------------------------------------------------------------
__global__ __launch_bounds__(256) void k_dequant(const int* __restrict__ pw,
                                                 const float* __restrict__ sc,
                                                 __hip_bfloat16* __restrict__ W) {
    int t = blockIdx.x * 256 + threadIdx.x;
    int row = t >> 8;
    int w0 = (t & 255) << 3;
    const int* p = pw + (size_t)row * 2048 + w0;
    int4 q0 = *(const int4*)p;
    int4 q1 = *(const int4*)(p + 4);
    float s = sc[row * 128 + (w0 >> 4)];
    float ns8 = -8.0f * s;
    int w[8] = {q0.x, q0.y, q0.z, q0.w, q1.x, q1.y, q1.z, q1.w};
    __hip_bfloat162 o[8];
#pragma unroll
    for (int i = 0; i < 8; ++i) {
        float lo = fmaf((float)(w[i] & 15), s, ns8);
        float hi = fmaf((float)(w[i] >> 4), s, ns8);
        o[i] = __float22bfloat162_rn(make_float2(lo, hi));
    }
    __hip_bfloat16* dst = W + (size_t)row * 4096 + w0 * 2;
    *(int4*)dst = *(int4*)&o[0];
    *(int4*)(dst + 8) = *(int4*)&o[4];
}

// ---------------------------------------------------------------------------
// Kernel 2 (tier A): r15 (r8 schedule + row-major LDS) with FULL-DEPTH XOR
// swizzle (G4): shorts  k' = k ^ ((row&7)<<3)   [bytes: ^ (row&7)<<4].
// r15's 1-bit st_16x32 left a 4-way conflict (5.03e7): groups of 8
// consecutive lanes read 8 rows at the same byte-slot (row stride 128B =
// full bank wrap); 1 XOR bit -> 2 slots. 3-bit XOR -> 8 distinct 16B slots
// -> all 32 banks per pass -> 0-conflict (rows 8-15 repeat = free 2-way).
// k-local = kk*32 | kb (disjoint bits) so read addr(kk=1) = roff ^ 32
// (per-lane const). DMA dest linear; SOURCE carries the same involution:
// thread t: row = g*64 + (t>>3), k = (t&7)*8 ^ ((t>>3)&7)*8  (permutes
// 16B chunks within one 128B row -> coalescing preserved).
// Everything else byte-identical to r15 (race-audited r8 schedule).
// ---------------------------------------------------------------------------
__global__ __launch_bounds__(512, 2) void k_gemm16(const __hip_bfloat16* __restrict__ Xb,
                                                   const __hip_bfloat16* __restrict__ Wb,
                                                   float* __restrict__ out) {
    __shared__ __align__(16) short L[2][2][2][8192];  // [buf][A/B][half][16KB]

    int bid = blockIdx.x;
    int swz = (bid & 7) * 128 + (bid >> 3);           // XCD-bijective (1024%8==0)
    int bn = swz & 15, bm = swz >> 4;
    int m0 = bm * 256, n0 = bn * 256;
    int t = threadIdx.x, lane = t & 63, wv = t >> 6;
    int wm = wv >> 2, wn = wv & 3, wnh = wn >> 1;

    // staging source (pre-swizzled, 3-bit XOR): row g*64+(t>>3),
    // k = (t&7)*8 ^ ((t>>3)&7)*8
    int srow = t >> 3;                       // 0..63 (g adds 64; (row&7) unchanged)
    int sko = ((t & 7) * 8) ^ (((t >> 3) & 7) * 8);
    const __hip_bfloat16* gA = Xb + (size_t)(m0 + srow) * K_TOTAL + sko;
    const __hip_bfloat16* gB = Wb + (size_t)(n0 + srow) * K_TOTAL + sko;

    auto stA = [&](int b, int h, int s_) {
        gload_lds16(gA + (size_t)(h * 128) * K_TOTAL + s_ * 64, &L[b][0][h][t * 8]);
        gload_lds16(gA + (size_t)(h * 128 + 64) * K_TOTAL + s_ * 64, &L[b][0][h][4096 + t * 8]);
    };
    auto stB = [&](int b, int h, int s_) {
        gload_lds16(gB + (size_t)(h * 128) * K_TOTAL + s_ * 64, &L[b][1][h][t * 8]);
        gload_lds16(gB + (size_t)(h * 128 + 64) * K_TOTAL + s_ * 64, &L[b][1][h][4096 + t * 8]);
    };

    // frag-read lane constants (3-bit XOR)
    const int l15 = lane & 15;
    const int kb = (lane >> 4) * 8;                       // 0,8,16,24
    const int kx = kb ^ ((l15 & 7) << 3);                 // full-depth XOR
    const int roff = l15 * 64 + kx;                       // kk=0
    const int roff2 = roff ^ 32;                          // kk=1 (XOR, not +)
    const int bco = (wn & 1) * 4096;

    f32x4 acc[8][4];
#pragma unroll
    for (int f = 0; f < 8; ++f)
#pragma unroll
        for (int j = 0; j < 4; ++j) acc[f][j] = (f32x4)(0.0f);

    bf16x8 Af[8], Bq01[4], Bq23[4];

#define RD_A(rfb) { _Pragma("unroll") for (int rf = 0; rf < 4; ++rf) { \
        Af[rf * 2]     = *(const bf16x8*)&LA[((rfb) + rf) * 1024 + roff]; \
        Af[rf * 2 + 1] = *(const bf16x8*)&LA[((rfb) + rf) * 1024 + roff2]; } }
#define RD_B(dst, cfb) { _Pragma("unroll") for (int cf = 0; cf < 2; ++cf) { \
        dst[cf * 2]     = *(const bf16x8*)&LB[bco + ((cfb) + cf) * 1024 + roff]; \
        dst[cf * 2 + 1] = *(const bf16x8*)&LB[bco + ((cfb) + cf) * 1024 + roff2]; } }
#define MM16(rfb, Bv, cfb) { _Pragma("unroll") for (int kk = 0; kk < 2; ++kk) \
        _Pragma("unroll") for (int rf = 0; rf < 4; ++rf) \
        _Pragma("unroll") for (int cf = 0; cf < 2; ++cf) \
            acc[(rfb) + rf][(cfb) + cf] = __builtin_amdgcn_mfma_f32_16x16x32_bf16( \
                Af[rf * 2 + kk], Bv[cf * 2 + kk], acc[(rfb) + rf][(cfb) + cf], 0, 0, 0); }
#define BAR __builtin_amdgcn_s_barrier()
#define PRI(x) __builtin_amdgcn_s_setprio(x)
#define VMW(n) { asm volatile("s_waitcnt vmcnt(" #n ")" ::: "memory"); \
                 __builtin_amdgcn_sched_barrier(0); }

    // ---- prologue (r8-identical): B(0), A(0), B(1); vmcnt(4) ----
    stB(0, 0, 0); stB(0, 1, 0);
    stA(0, 0, 0); stA(0, 1, 0);
    stB(1, 0, 1); stB(1, 1, 1);
    VMW(4);
    BAR;

    for (int i = 0; i < NSTEP / 2; ++i) {
        const int s = 2 * i;
        const bool g = (s + 2 < NSTEP);
        // ======== K-step s (buf 0) ========
        {
            const short* LA = &L[0][0][wm][0];
            const short* LB = &L[0][1][wnh][0];
            // p1
            RD_A(0) RD_B(Bq01, 0)
            stA(1, 0, s + 1);
            BAR; PRI(1); MM16(0, Bq01, 0) PRI(0); BAR;
            // p2
            RD_B(Bq23, 2)
            stA(1, 1, s + 1);
            BAR; PRI(1); MM16(0, Bq23, 2) PRI(0); BAR;
            // p3
            RD_A(4)
            if (g) stB(0, 0, s + 2);
            BAR; PRI(1); MM16(4, Bq01, 0) PRI(0); BAR;
            // p4
            if (g) stB(0, 1, s + 2);
            BAR; PRI(1); MM16(4, Bq23, 2) PRI(0);
            if (g) { VMW(4) } else { VMW(0) }
            BAR;
        }
        // ======== K-step s+1 (buf 1) ========
        {
            const short* LA = &L[1][0][wm][0];
            const short* LB = &L[1][1][wnh][0];
            // p5
            RD_A(0) RD_B(Bq01, 0)
            if (g) stA(0, 0, s + 2);
            BAR; PRI(1); MM16(0, Bq01, 0) PRI(0); BAR;
            // p6
            RD_B(Bq23, 2)
            if (g) stA(0, 1, s + 2);
            BAR; PRI(1); MM16(0, Bq23, 2) PRI(0); BAR;
            // p7
            RD_A(4)
            if (g) stB(1, 0, s + 3);
            BAR; PRI(1); MM16(4, Bq01, 0) PRI(0); BAR;
            // p8
            if (g) stB(1, 1, s + 3);
            BAR; PRI(1); MM16(4, Bq23, 2) PRI(0);
            if (g) { VMW(4) } else { VMW(0) }
            BAR;
        }
    }
#undef RD_A
#undef RD_B
#undef MM16
#undef BAR
#undef PRI
#undef VMW

    // ---- epilogue: C/D layout col=lane&15, row=(lane>>4)*4+reg ----
    int col0 = n0 + wn * 64 + l15;
    int row0 = m0 + wm * 128 + (lane >> 4) * 4;
#pragma unroll
    for (int f = 0; f < 8; ++f)
#pragma unroll
        for (int j = 0; j < 4; ++j) {
            f32x4 v = acc[f][j];
            int r = row0 + f * 16;
            int c = col0 + j * 16;
#pragma unroll
            for (int q = 0; q < 4; ++q)
                out[(size_t)(r + q) * N_TOTAL + c] = v[q];
        }
}

// ---------------------------------------------------------------------------
// Tier B: m97-structure GEMM, A reg-staged from f32 X (round-5 verified).
// ---------------------------------------------------------------------------
__global__ __launch_bounds__(256) void k_gemm2b(const float* __restrict__ X,
                                                const __hip_bfloat16* __restrict__ Wb,
                                                float* __restrict__ out) {
    __shared__ __align__(16) short As[128 * 32];
    __shared__ __align__(16) short Bs[128 * 32];
    int bid = blockIdx.x;
    int swz = (bid & 7) * 512 + (bid >> 3);
    int bn = swz & 31, bm = swz >> 5;
    int m0 = bm * 128, n0 = bn * 128;
    int t = threadIdx.x, lane = t & 63, wv = t >> 6;
    int wr = wv >> 1, wc = wv & 1;
    f32x4 acc[4][4];
#pragma unroll
    for (int i = 0; i < 4; ++i)
#pragma unroll
        for (int j = 0; j < 4; ++j) acc[i][j] = (f32x4)(0.0f);
    int arow = t >> 2, acol = (t & 3) * 8;
    const float* Agf0 = X + (size_t)(m0 + arow) * K_TOTAL + acol;
    const float* Agf1 = Agf0 + (size_t)64 * K_TOTAL;
    const __hip_bfloat16* Bg0 = Wb + (size_t)(n0 + arow) * K_TOTAL + acol;
    const __hip_bfloat16* Bg1 = Bg0 + (size_t)64 * K_TOTAL;
    float4 xa0 = *(const float4*)(Agf0), xa1 = *(const float4*)(Agf0 + 4);
    float4 xb0 = *(const float4*)(Agf1), xb1 = *(const float4*)(Agf1 + 4);
    for (int kt = 0; kt < NT32; ++kt) {
        if (kt) __syncthreads();
        __hip_bfloat162 oa[4] = {
            __float22bfloat162_rn(make_float2(xa0.x, xa0.y)),
            __float22bfloat162_rn(make_float2(xa0.z, xa0.w)),
            __float22bfloat162_rn(make_float2(xa1.x, xa1.y)),
            __float22bfloat162_rn(make_float2(xa1.z, xa1.w))};
        __hip_bfloat162 ob[4] = {
            __float22bfloat162_rn(make_float2(xb0.x, xb0.y)),
            __float22bfloat162_rn(make_float2(xb0.z, xb0.w)),
            __float22bfloat162_rn(make_float2(xb1.x, xb1.y)),
            __float22bfloat162_rn(make_float2(xb1.z, xb1.w))};
        *(int4*)&As[t * 8] = *(int4*)&oa[0];
        *(int4*)&As[2048 + t * 8] = *(int4*)&ob[0];
        gload_lds16(Bg0 + kt * 32, &Bs[t * 8]);
        gload_lds16(Bg1 + kt * 32, &Bs[2048 + t * 8]);
        __syncthreads();
        if (kt < NT32 - 1) {
            int ko = (kt + 1) * 32;
            xa0 = *(const float4*)(Agf0 + ko);
            xa1 = *(const float4*)(Agf0 + ko + 4);
            xb0 = *(const float4*)(Agf1 + ko);
            xb1 = *(const float4*)(Agf1 + ko + 4);
        }
        bf16x8 a[4], b[4];
        int ro = (lane & 15) * 32 + (lane >> 4) * 8;
#pragma unroll
        for (int i = 0; i < 4; ++i)
            a[i] = *(const bf16x8*)&As[(wr * 64 + i * 16) * 32 + ro];
#pragma unroll
        for (int j = 0; j < 4; ++j)
            b[j] = *(const bf16x8*)&Bs[(wc * 64 + j * 16) * 32 + ro];
#pragma unroll
        for (int i = 0; i < 4; ++i)
#pragma unroll
            for (int j = 0; j < 4; ++j)
                acc[i][j] = __builtin_amdgcn_mfma_f32_16x16x32_bf16(a[i], b[j], acc[i][j], 0, 0, 0);
    }
    int col0 = n0 + wc * 64 + (lane & 15);
    int row0 = m0 + wr * 64 + (lane >> 4) * 4;
#pragma unroll
    for (int i = 0; i < 4; ++i)
#pragma unroll
        for (int j = 0; j < 4; ++j) {
            f32x4 v = acc[i][j];
            int r = row0 + i * 16, c = col0 + j * 16;
#pragma unroll
            for (int q = 0; q < 4; ++q)
                out[(size_t)(r + q) * N_TOTAL + c] = v[q];
        }
}

extern "C" void kernel_launch(void* const* d_in, const int* in_sizes, int n_in,
                              void* d_out, int out_size, void* d_ws, size_t ws_size,
                              hipStream_t stream) {
    const float* X = (const float*)d_in[0];
    const int* PW = (const int*)d_in[1];
    const float* SC = (const float*)d_in[2];
    float* OUT = (float*)d_out;

    const size_t needW = (size_t)N_TOTAL * K_TOTAL * 2;            // 33.5 MB
    const size_t needX = needW + (size_t)M_TOTAL * K_TOTAL * 2;    // +134 MB

    if (ws_size >= needX) {
        __hip_bfloat16* Wb = (__hip_bfloat16*)d_ws;
        __hip_bfloat16* Xb = (__hip_bfloat16*)((char*)d_ws + needW);
        k_convX<<<dim3(32768), dim3(256), 0, stream>>>(X, Xb);
        k_dequant<<<dim3(4096), dim3(256), 0, stream>>>(PW, SC, Wb);
        k_gemm16<<<dim3((M_TOTAL / 256) * (N_TOTAL / 256)), dim3(512), 0, stream>>>(Xb, Wb, OUT);
    } else if (ws_size >= needW) {
        __hip_bfloat16* Wb = (__hip_bfloat16*)d_ws;
        k_dequant<<<dim3(4096), dim3(256), 0, stream>>>(PW, SC, Wb);
        k_gemm2b<<<dim3((M_TOTAL / 128) * (N_TOTAL / 128)), dim3(256), 0, stream>>>(X, Wb, OUT);
    }
}